// Round 3
// baseline (403.253 us; speedup 1.0000x reference)
//
#include <hip/hip_runtime.h>
#include <math.h>

#define LOG2E 1.4426950408889634f
#define LN2F  0.6931471805599453f

constexpr int M   = 2048;
constexpr int N   = 2048;
constexpr int D   = 256;
constexpr int MP1 = 2049;   // M+1 == N+1
constexpr int UVS = 2052;   // padded u/v batch stride -> float4-aligned rows
constexpr int NCHUNK = 64;
constexpr int CHUNK  = 32;  // NCHUNK*CHUNK == 2048 score rows; dustbin row added in combine

__device__ inline float fast_exp2(float x) {
#if __has_builtin(__builtin_amdgcn_exp2f)
    return __builtin_amdgcn_exp2f(x);
#else
    return exp2f(x);
#endif
}
__device__ inline float fast_log2(float x) {
#if __has_builtin(__builtin_amdgcn_logf)
    return __builtin_amdgcn_logf(x);   // v_log_f32 is log2
#else
    return log2f(x);
#endif
}
// NaN-guarded exp2 for identity (-inf) merges
__device__ inline float exp2g(float x) { return fast_exp2(fmaxf(x, -20000.0f)); }

__device__ inline void insert5(float t[5], float y) {
    float v = y, mx;
    #pragma unroll
    for (int k = 0; k < 5; ++k) { mx = fmaxf(t[k], v); v = fminf(t[k], v); t[k] = mx; }
}

// descending compare-exchange: a <- max, b <- min
__device__ inline void ce_desc(float& a, float& b) {
    float hi = fmaxf(a, b), lo = fminf(a, b); a = hi; b = lo;
}
// 19-CE sorting network for 8 elements, descending (y[0] = max). ILP-friendly.
__device__ inline void sort8_desc(float y[8]) {
    ce_desc(y[0],y[1]); ce_desc(y[2],y[3]); ce_desc(y[4],y[5]); ce_desc(y[6],y[7]);
    ce_desc(y[0],y[2]); ce_desc(y[1],y[3]); ce_desc(y[4],y[6]); ce_desc(y[5],y[7]);
    ce_desc(y[1],y[2]); ce_desc(y[5],y[6]); ce_desc(y[0],y[4]); ce_desc(y[3],y[7]);
    ce_desc(y[1],y[5]); ce_desc(y[2],y[6]);
    ce_desc(y[1],y[4]); ce_desc(y[3],y[6]);
    ce_desc(y[2],y[4]); ce_desc(y[3],y[5]);
    ce_desc(y[3],y[4]);
}

// merge sorted-desc top5 lists + lse states
__device__ inline void merge5(float a[5], float& as, const float b[5], float bs) {
    float r0 = fmaxf(a[0], b[0]);
    float r1 = fmaxf(fmaxf(a[1], b[1]), fminf(a[0], b[0]));
    float r2 = fmaxf(fmaxf(a[2], b[2]), fmaxf(fminf(a[1], b[0]), fminf(a[0], b[1])));
    float r3 = fmaxf(fmaxf(a[3], b[3]),
               fmaxf(fmaxf(fminf(a[2], b[0]), fminf(a[1], b[1])), fminf(a[0], b[2])));
    float r4 = fmaxf(fmaxf(a[4], b[4]),
               fmaxf(fmaxf(fminf(a[3], b[0]), fminf(a[2], b[1])),
                     fmaxf(fminf(a[1], b[2]), fminf(a[0], b[3]))));
    as = as * exp2g(a[0] - r0) + bs * exp2g(b[0] - r0);
    a[0] = r0; a[1] = r1; a[2] = r2; a[3] = r3; a[4] = r4;
}

__device__ inline void merge5_shfl_xor(float t[5], float& s, int off) {
    float b[5], bs;
    #pragma unroll
    for (int k = 0; k < 5; ++k) b[k] = __shfl_xor(t[k], off, 64);
    bs = __shfl_xor(s, off, 64);
    merge5(t, s, b, bs);
}

// dual butterfly level: two independent states interleaved
__device__ inline void merge5_shfl_xor2(float tA[5], float& sA, float tB[5], float& sB, int off) {
    float bA[5], bB[5];
    #pragma unroll
    for (int k = 0; k < 5; ++k) { bA[k] = __shfl_xor(tA[k], off, 64); bB[k] = __shfl_xor(tB[k], off, 64); }
    float bsA = __shfl_xor(sA, off, 64);
    float bsB = __shfl_xor(sB, off, 64);
    merge5(tA, sA, bA, bsA);
    merge5(tB, sB, bB, bsB);
}

// online add of one element to (t,s) state
__device__ inline void online_add(float t[5], float& s, float y) {
    float m_old = t[0];
    float m_new = fmaxf(m_old, y);
    s = s * exp2g(m_old - m_new) + fast_exp2(y - m_new);
    insert5(t, y);
}

// sort a group of 8, compute group lse-state, fold into accumulator.
__device__ inline void group_accum(bool first, float t[5], float& s, float z[8]) {
    sort8_desc(z);
    float gs = 1.0f;
    #pragma unroll
    for (int k = 1; k < 8; ++k) gs += fast_exp2(z[k] - z[0]);
    if (first) { t[0]=z[0]; t[1]=z[1]; t[2]=z[2]; t[3]=z[3]; t[4]=z[4]; s = gs; }
    else merge5(t, s, z, gs);
}

__device__ inline float gelu_exact(float x) {
    return 0.5f * x * (1.0f + erff(x * 0.70710678118654752f));
}

__device__ inline float wave_sum(float x) {
    #pragma unroll
    for (int off = 32; off >= 1; off >>= 1) x += __shfl_xor(x, off, 64);
    return x;
}
__device__ inline void wave_sum2(float& x, float& y) {
    #pragma unroll
    for (int off = 32; off >= 1; off >>= 1) {
        float xs = __shfl_xor(x, off, 64);
        float ys = __shfl_xor(y, off, 64);
        x += xs; y += ys;
    }
}

// one-wave MLP: 16 -> 64 gelu LN -> 64 gelu LN -> 1. f[] lane-uniform, j = lane.
__device__ inline float mlp_wave(const float f[16], int j,
    const float* __restrict__ w1, const float* __restrict__ b1,
    const float* __restrict__ g1, const float* __restrict__ be1,
    const float* __restrict__ w2, const float* __restrict__ b2,
    const float* __restrict__ g2, const float* __restrict__ be2,
    const float* __restrict__ w3, const float* __restrict__ b3)
{
    float h = b1[j];
    #pragma unroll
    for (int k = 0; k < 16; ++k) h = fmaf(f[k], w1[j * 16 + k], h);
    h = gelu_exact(h);
    float mu  = wave_sum(h) * (1.0f / 64.0f);
    float d   = h - mu;
    float var = wave_sum(d * d) * (1.0f / 64.0f);
    float hn  = d * rsqrtf(var + 1e-5f) * g1[j] + be1[j];
    float h2 = b2[j];
    #pragma unroll
    for (int k = 0; k < 64; ++k) h2 = fmaf(__shfl(hn, k, 64), w2[j * 64 + k], h2);
    h2 = gelu_exact(h2);
    mu  = wave_sum(h2) * (1.0f / 64.0f);
    d   = h2 - mu;
    var = wave_sum(d * d) * (1.0f / 64.0f);
    float hn2 = d * rsqrtf(var + 1e-5f) * g2[j] + be2[j];
    return wave_sum(hn2 * w3[j]) + b3[0];
}

// dual MLP: two independent rows through the same weights
__device__ inline void mlp_wave2(const float fA[16], const float fB[16], int j,
    const float* __restrict__ w1, const float* __restrict__ b1,
    const float* __restrict__ g1, const float* __restrict__ be1,
    const float* __restrict__ w2, const float* __restrict__ b2,
    const float* __restrict__ g2, const float* __restrict__ be2,
    const float* __restrict__ w3, const float* __restrict__ b3,
    float& oA, float& oB)
{
    float hA = b1[j], hB = hA;
    #pragma unroll
    for (int k = 0; k < 16; ++k) {
        float w = w1[j * 16 + k];
        hA = fmaf(fA[k], w, hA);
        hB = fmaf(fB[k], w, hB);
    }
    hA = gelu_exact(hA); hB = gelu_exact(hB);
    float muA = hA, muB = hB;
    wave_sum2(muA, muB);
    muA *= (1.0f / 64.0f); muB *= (1.0f / 64.0f);
    float dA = hA - muA, dB = hB - muB;
    float vA = dA * dA, vB = dB * dB;
    wave_sum2(vA, vB);
    vA *= (1.0f / 64.0f); vB *= (1.0f / 64.0f);
    float hnA = dA * rsqrtf(vA + 1e-5f) * g1[j] + be1[j];
    float hnB = dB * rsqrtf(vB + 1e-5f) * g1[j] + be1[j];

    float a0A = b2[j], a1A = 0.0f, a0B = b2[j], a1B = 0.0f;
    #pragma unroll
    for (int k = 0; k < 64; k += 2) {
        float w0 = w2[j * 64 + k], w1v = w2[j * 64 + k + 1];
        float sA0 = __shfl(hnA, k, 64),     sB0 = __shfl(hnB, k, 64);
        float sA1 = __shfl(hnA, k + 1, 64), sB1 = __shfl(hnB, k + 1, 64);
        a0A = fmaf(sA0, w0, a0A); a0B = fmaf(sB0, w0, a0B);
        a1A = fmaf(sA1, w1v, a1A); a1B = fmaf(sB1, w1v, a1B);
    }
    float h2A = gelu_exact(a0A + a1A), h2B = gelu_exact(a0B + a1B);
    muA = h2A; muB = h2B;
    wave_sum2(muA, muB);
    muA *= (1.0f / 64.0f); muB *= (1.0f / 64.0f);
    dA = h2A - muA; dB = h2B - muB;
    vA = dA * dA; vB = dB * dB;
    wave_sum2(vA, vB);
    vA *= (1.0f / 64.0f); vB *= (1.0f / 64.0f);
    float hn2A = dA * rsqrtf(vA + 1e-5f) * g2[j] + be2[j];
    float hn2B = dB * rsqrtf(vB + 1e-5f) * g2[j] + be2[j];
    float zA = hn2A * w3[j], zB = hn2B * w3[j];
    wave_sum2(zA, zB);
    oA = zA + b3[0];
    oB = zB + b3[0];
}

__device__ inline void feats_from(const float t[5], float s, float l2w,
                                  const float* __restrict__ dd, float f[16], float& un)
{
    float lse = t[0] + fast_log2(s);
    un = l2w - lse;
    f[0] = l2w * LN2F;
    f[1] = un  * LN2F;
    f[2] = 0.0f;
    f[3] = (t[0] - t[1]) * LN2F;
    f[4] = (t[0] - t[2]) * LN2F;
    f[5] = (t[0] - t[3]) * LN2F;
    f[6] = (t[0] - t[4]) * LN2F;
    f[7] = (lse - t[0]) * LN2F;
    #pragma unroll
    for (int p = 0; p < 8; ++p) f[8 + p] = dd[p];
}

// ---------------------------------------------------------------------------
// dA[b,m,p] = sum_d mdesc[b,d,m] * pw[p,d] + pb[p];  dustbin row m==M -> 0
// grid (9, B, 2), block 256
// ---------------------------------------------------------------------------
__global__ __launch_bounds__(256) void proj_kernel(
    const float* __restrict__ mdesc0, const float* __restrict__ mdesc1,
    const float* __restrict__ pA_w, const float* __restrict__ pA_b,
    const float* __restrict__ pB_w, const float* __restrict__ pB_b,
    float* __restrict__ dA, float* __restrict__ dB)
{
    const int which = blockIdx.z;
    const float* mdesc = which ? mdesc1 : mdesc0;
    const float* pw    = which ? pB_w : pA_w;
    const float* pb    = which ? pB_b : pA_b;
    float* dOut        = which ? dB   : dA;

    __shared__ float swT[D * 8];   // transposed: swT[d*8+p]
    const int tid = threadIdx.x;
    for (int idx = tid; idx < 8 * D; idx += 256) {
        int p = idx >> 8, d = idx & (D - 1);
        swT[d * 8 + p] = pw[idx];
    }
    __syncthreads();

    const int m = blockIdx.x * 256 + tid;
    const int b = blockIdx.y;
    if (m > M) return;
    float* out = dOut + ((size_t)b * MP1 + m) * 8;
    if (m == M) {
        #pragma unroll
        for (int p = 0; p < 8; ++p) out[p] = 0.0f;
        return;
    }
    float acc[8];
    #pragma unroll
    for (int p = 0; p < 8; ++p) acc[p] = pb[p];
    const float* base = mdesc + (size_t)b * D * M + m;
    #pragma unroll 4
    for (int d = 0; d < D; ++d) {
        float x = base[(size_t)d * M];
        #pragma unroll
        for (int p = 0; p < 8; ++p) acc[p] = fmaf(x, swT[d * 8 + p], acc[p]);
    }
    #pragma unroll
    for (int p = 0; p < 8; ++p) out[p] = acc[p];
}

// ---------------------------------------------------------------------------
// Row streaming reduce (NO MLP): grid (513, B), block 256 = 4 waves,
// ONE row per wave. 8 score float4 + 8 v float4 per lane, 4 sort8-groups,
// 6-level butterfly, 32 B state store. Short serial tail -> latency hiding.
// ---------------------------------------------------------------------------
__global__ __launch_bounds__(256) void row_stream(
    const float* __restrict__ scores, const float* __restrict__ alpha,
    const float* __restrict__ v, float* __restrict__ rowstate, int first_iter)
{
    const int tid  = threadIdx.x;
    const int lane = tid & 63;
    const int wv   = tid >> 6;
    const int r    = blockIdx.x * 4 + wv;
    if (r >= MP1) return;
    const int b = blockIdx.y;

    const float alpha2 = alpha[0] * LOG2E;
    const float4* v4 = (const float4*)(v + (size_t)b * UVS);

    float t[5], s;
    if (r < M) {
        const float4* s4 = (const float4*)(scores + ((size_t)b * M + r) * N);
        // half 1: groups 0,1
        #pragma unroll
        for (int h = 0; h < 2; ++h) {
            float4 q[4], w[4];
            #pragma unroll
            for (int j = 0; j < 4; ++j) q[j] = s4[lane + 64 * (4 * h + j)];
            if (!first_iter) {
                #pragma unroll
                for (int j = 0; j < 4; ++j) w[j] = v4[lane + 64 * (4 * h + j)];
            }
            #pragma unroll
            for (int gg = 0; gg < 2; ++gg) {
                float4 qa = q[2 * gg], qb = q[2 * gg + 1];
                float z[8];
                if (first_iter) {
                    z[0]=qa.x*LOG2E; z[1]=qa.y*LOG2E; z[2]=qa.z*LOG2E; z[3]=qa.w*LOG2E;
                    z[4]=qb.x*LOG2E; z[5]=qb.y*LOG2E; z[6]=qb.z*LOG2E; z[7]=qb.w*LOG2E;
                } else {
                    float4 wa = w[2 * gg], wb = w[2 * gg + 1];
                    z[0]=fmaf(qa.x,LOG2E,wa.x); z[1]=fmaf(qa.y,LOG2E,wa.y);
                    z[2]=fmaf(qa.z,LOG2E,wa.z); z[3]=fmaf(qa.w,LOG2E,wa.w);
                    z[4]=fmaf(qb.x,LOG2E,wb.x); z[5]=fmaf(qb.y,LOG2E,wb.y);
                    z[6]=fmaf(qb.z,LOG2E,wb.z); z[7]=fmaf(qb.w,LOG2E,wb.w);
                }
                group_accum(h == 0 && gg == 0, t, s, z);
            }
        }
    } else {   // dustbin row: z = alpha2 (+ v[c])
        #pragma unroll
        for (int g = 0; g < 4; ++g) {
            float z[8];
            if (first_iter) {
                #pragma unroll
                for (int k = 0; k < 8; ++k) z[k] = alpha2;
            } else {
                float4 wa = v4[lane + 128 * g];
                float4 wb = v4[lane + 128 * g + 64];
                z[0]=alpha2+wa.x; z[1]=alpha2+wa.y; z[2]=alpha2+wa.z; z[3]=alpha2+wa.w;
                z[4]=alpha2+wb.x; z[5]=alpha2+wb.y; z[6]=alpha2+wb.z; z[7]=alpha2+wb.w;
            }
            group_accum(g == 0, t, s, z);
        }
    }

    #pragma unroll
    for (int off = 32; off >= 1; off >>= 1) merge5_shfl_xor(t, s, off);

    if (lane == 0) {
        float4* st = (float4*)(rowstate + (size_t)(b * MP1 + r) * 8);
        st[0] = make_float4(t[0], t[1], t[2], t[3]);
        st[1] = make_float4(t[4], s, 0.0f, 0.0f);
    }
}

// ---------------------------------------------------------------------------
// Row MLP: grid (257, B), block 256 = 4 waves, TWO rows per wave.
// States read via wave-uniform (scalar) loads; dustbin-column online_add here;
// dual MLP; write u. Off the streaming critical path.
// ---------------------------------------------------------------------------
__global__ __launch_bounds__(256) void row_mlp(
    const float* __restrict__ rowstate, const float* __restrict__ alpha,
    const float* __restrict__ v, const float* __restrict__ dA,
    float* __restrict__ u, int first_iter,
    const float* __restrict__ w1, const float* __restrict__ b1,
    const float* __restrict__ g1, const float* __restrict__ be1,
    const float* __restrict__ w2, const float* __restrict__ b2,
    const float* __restrict__ g2, const float* __restrict__ be2,
    const float* __restrict__ w3, const float* __restrict__ b3)
{
    const int tid  = threadIdx.x;
    const int lane = tid & 63;
    const int wv   = tid >> 6;
    const int pair = blockIdx.x * 4 + wv;
    const int r0   = pair * 2;
    if (r0 >= MP1) return;
    const int b = blockIdx.y;
    const float alpha2 = alpha[0] * LOG2E;
    const float extra = first_iter ? alpha2 : (alpha2 + v[(size_t)b * UVS + N]);

    const float4* st = (const float4*)(rowstate + (size_t)(b * MP1 + r0) * 8);
    if (r0 < M) {
        float4 a0 = st[0], a1 = st[1], b0 = st[2], b1v = st[3];
        float tA[5] = {a0.x, a0.y, a0.z, a0.w, a1.x}; float sA = a1.y;
        float tB[5] = {b0.x, b0.y, b0.z, b0.w, b1v.x}; float sB = b1v.y;
        online_add(tA, sA, extra);
        online_add(tB, sB, extra);

        float fA[16], fB[16], unA, unB;
        const float* ddA = dA + (size_t)(b * MP1 + r0) * 8;
        feats_from(tA, sA, -12.0f, ddA, fA, unA);
        feats_from(tB, sB, -12.0f, ddA + 8, fB, unB);

        float oA, oB;
        mlp_wave2(fA, fB, lane, w1, b1, g1, be1, w2, b2, g2, be2, w3, b3, oA, oB);
        if (lane == 0) {
            u[(size_t)b * UVS + r0]     = unA + oA * LOG2E;
            u[(size_t)b * UVS + r0 + 1] = unB + oB * LOG2E;
        }
    } else {   // r0 == M: dustbin row, single
        float4 a0 = st[0], a1 = st[1];
        float t[5] = {a0.x, a0.y, a0.z, a0.w, a1.x}; float s = a1.y;
        online_add(t, s, extra);

        float f[16], un;
        const float* dd = dA + (size_t)(b * MP1 + M) * 8;
        feats_from(t, s, -1.0f, dd, f, un);
        float o = mlp_wave(f, lane, w1, b1, g1, be1, w2, b2, g2, be2, w3, b3);
        if (lane == 0) u[(size_t)b * UVS + M] = un + o * LOG2E;
    }
}

// ---------------------------------------------------------------------------
// Col pass: grid (4, NCHUNK=64, B), block 256 = 4096 waves (4/SIMD).
// Thread owns TWO columns (float2 loads), reduces CHUNK=32 rows as 4
// sort8-groups per column. u reads are wave-uniform (scalar loads).
// partial layout: [b][chunk][c][8]
// ---------------------------------------------------------------------------
__global__ __launch_bounds__(256) void col_stream(
    const float* __restrict__ scores,
    const float* __restrict__ u, float* __restrict__ partial)
{
    const int tid = threadIdx.x;
    const int chunk = blockIdx.y;
    const int b = blockIdx.z;
    const int r0 = chunk * CHUNK;
    const int c0 = blockIdx.x * 512 + tid * 2;

    const float* __restrict__ ub = u + (size_t)b * UVS + r0;
    const float2* base2 = (const float2*)(scores + (size_t)b * M * N + (size_t)r0 * N) + (c0 >> 1);

    float tA[5], sA, tB[5], sB;
    #pragma unroll
    for (int g = 0; g < 4; ++g) {
        float2 q[8];
        #pragma unroll
        for (int k = 0; k < 8; ++k) q[k] = base2[(size_t)(8 * g + k) * (N / 2)];
        float zA[8], zB[8];
        #pragma unroll
        for (int k = 0; k < 8; ++k) {
            float uu = ub[8 * g + k];
            zA[k] = fmaf(q[k].x, LOG2E, uu);
            zB[k] = fmaf(q[k].y, LOG2E, uu);
        }
        group_accum(g == 0, tA, sA, zA);
        group_accum(g == 0, tB, sB, zB);
    }

    float4* pq = (float4*)(partial + (((size_t)(b * NCHUNK + chunk) * MP1) + c0) * 8);
    pq[0] = make_float4(tA[0], tA[1], tA[2], tA[3]);
    pq[1] = make_float4(tA[4], sA, 0.0f, 0.0f);
    pq[2] = make_float4(tB[0], tB[1], tB[2], tB[3]);
    pq[3] = make_float4(tB[4], sB, 0.0f, 0.0f);
}

// ---------------------------------------------------------------------------
// Col combine + fused MLP: grid (257, B), block 256 = 4 waves, TWO cols per
// wave. All 64 lanes load one chunk-partial (NCHUNK=64); dual butterfly;
// dustbin row add; dual MLP. Dustbin column (c==N) wave reduces alpha2+u[].
// ---------------------------------------------------------------------------
__global__ __launch_bounds__(256) void col_mlp_fused(
    const float* __restrict__ partial, const float* __restrict__ dB,
    const float* __restrict__ u, const float* __restrict__ alpha,
    float* __restrict__ v,
    const float* __restrict__ w1, const float* __restrict__ b1,
    const float* __restrict__ g1, const float* __restrict__ be1,
    const float* __restrict__ w2, const float* __restrict__ b2,
    const float* __restrict__ g2, const float* __restrict__ be2,
    const float* __restrict__ w3, const float* __restrict__ b3)
{
    const int tid  = threadIdx.x;
    const int lane = tid & 63;
    const int wv   = tid >> 6;
    const int pair = blockIdx.x * 4 + wv;
    const int c0   = pair * 2;
    if (c0 >= MP1) return;
    const int b = blockIdx.y;
    const float alpha2 = alpha[0] * LOG2E;
    const float uM = u[(size_t)b * UVS + M];

    if (c0 < N) {
        // ---- dual path: columns c0, c0+1; lane k holds chunk k's partial ----
        const float4* pq = (const float4*)(partial + (((size_t)(b * NCHUNK + lane) * MP1) + c0) * 8);
        float4 a0 = pq[0], a1 = pq[1], b0 = pq[2], b1v = pq[3];
        float tA[5] = {a0.x, a0.y, a0.z, a0.w, a1.x}; float sA = a1.y;
        float tB[5] = {b0.x, b0.y, b0.z, b0.w, b1v.x}; float sB = b1v.y;

        #pragma unroll
        for (int off = 32; off >= 1; off >>= 1) merge5_shfl_xor2(tA, sA, tB, sB, off);

        float extra = alpha2 + uM;   // dustbin row element
        online_add(tA, sA, extra);
        online_add(tB, sB, extra);

        float fA[16], fB[16], vnA, vnB;
        const float* ddA = dB + (size_t)(b * MP1 + c0) * 8;
        feats_from(tA, sA, -12.0f, ddA, fA, vnA);
        feats_from(tB, sB, -12.0f, ddA + 8, fB, vnB);

        float oA, oB;
        mlp_wave2(fA, fB, lane, w1, b1, g1, be1, w2, b2, g2, be2, w3, b3, oA, oB);
        if (lane == 0) {
            v[(size_t)b * UVS + c0]     = vnA + oA * LOG2E;
            v[(size_t)b * UVS + c0 + 1] = vnB + oB * LOG2E;
        }
    } else {
        // ---- dustbin column c == N: reduce alpha2 + u[r] over r=0..M ----
        const float4* u4 = (const float4*)(u + (size_t)b * UVS);
        float4 qq[8];
        #pragma unroll
        for (int j = 0; j < 8; ++j) qq[j] = u4[lane + 64 * j];
        float t[5], s;
        #pragma unroll
        for (int g = 0; g < 4; ++g) {
            float4 qa = qq[2 * g], qb = qq[2 * g + 1];
            float z[8];
            z[0]=alpha2+qa.x; z[1]=alpha2+qa.y; z[2]=alpha2+qa.z; z[3]=alpha2+qa.w;
            z[4]=alpha2+qb.x; z[5]=alpha2+qb.y; z[6]=alpha2+qb.z; z[7]=alpha2+qb.w;
            group_accum(g == 0, t, s, z);
        }
        #pragma unroll
        for (int off = 32; off >= 1; off >>= 1) merge5_shfl_xor(t, s, off);
        online_add(t, s, alpha2 + uM);   // corner element S[M,N]

        float f[16], vn;
        const float* dd = dB + (size_t)(b * MP1 + N) * 8;
        feats_from(t, s, -1.0f, dd, f, vn);
        float o = mlp_wave(f, lane, w1, b1, g1, be1, w2, b2, g2, be2, w3, b3);
        if (lane == 0) v[(size_t)b * UVS + N] = vn + o * LOG2E;
    }
}

// ---------------------------------------------------------------------------
// out[b,r,c] = S*LOG2E + u[b,r] + v[b,c] + 12.  grid (2049, B), block 256.
// ---------------------------------------------------------------------------
__global__ __launch_bounds__(256) void final_kernel(
    const float* __restrict__ scores, const float* __restrict__ alpha,
    const float* __restrict__ u, const float* __restrict__ v,
    float* __restrict__ out)
{
    const int r = blockIdx.x;
    const int b = blockIdx.y;
    const int tid = threadIdx.x;
    const float alpha2 = alpha[0] * LOG2E;
    const float* vb = v + (size_t)b * UVS;
    const float4* v4 = (const float4*)vb;
    const float ur = u[(size_t)b * UVS + r] + 12.0f;
    float* orow = out + ((size_t)b * MP1 + r) * MP1;

    if (r < M) {
        const float4* s4 = (const float4*)(scores + ((size_t)b * M + r) * N);
        #pragma unroll
        for (int k = 0; k < 2; ++k) {
            int j = tid + 256 * k;           // float4 index, c = 4j
            float4 sv = s4[j];
            float4 vv = v4[j];
            int c = 4 * j;
            orow[c]     = fmaf(sv.x, LOG2E, ur + vv.x);
            orow[c + 1] = fmaf(sv.y, LOG2E, ur + vv.y);
            orow[c + 2] = fmaf(sv.z, LOG2E, ur + vv.z);
            orow[c + 3] = fmaf(sv.w, LOG2E, ur + vv.w);
        }
    } else {
        #pragma unroll
        for (int k = 0; k < 2; ++k) {
            int j = tid + 256 * k;
            float4 vv = v4[j];
            int c = 4 * j;
            orow[c]     = alpha2 + ur + vv.x;
            orow[c + 1] = alpha2 + ur + vv.y;
            orow[c + 2] = alpha2 + ur + vv.z;
            orow[c + 3] = alpha2 + ur + vv.w;
        }
    }
    if (tid == 0) orow[N] = alpha2 + ur + vb[N];
}

extern "C" void kernel_launch(void* const* d_in, const int* in_sizes, int n_in,
                              void* d_out, int out_size, void* d_ws, size_t ws_size,
                              hipStream_t stream) {
    const float* scores = (const float*)d_in[0];
    const float* alpha  = (const float*)d_in[1];
    const float* mdesc0 = (const float*)d_in[2];
    const float* mdesc1 = (const float*)d_in[3];
    const float* pA_w = (const float*)d_in[4];
    const float* pA_b = (const float*)d_in[5];
    const float* pB_w = (const float*)d_in[6];
    const float* pB_b = (const float*)d_in[7];
    const float* rW[10]; const float* cW[10];
    for (int k = 0; k < 10; ++k) rW[k] = (const float*)d_in[8 + k];
    for (int k = 0; k < 10; ++k) cW[k] = (const float*)d_in[18 + k];
    float* out = (float*)d_out;

    const int B = in_sizes[0] / (M * N);

    float* ws = (float*)d_ws;
    float* u        = ws;                             // B*UVS
    float* v        = u + (size_t)B * UVS;            // B*UVS
    float* dA       = v + (size_t)B * UVS;            // B*MP1*8
    float* dB       = dA + (size_t)B * MP1 * 8;       // B*MP1*8
    float* rowstate = dB + (size_t)B * MP1 * 8;       // B*MP1*8
    float* partial  = rowstate + (size_t)B * MP1 * 8; // B*NCHUNK*MP1*8

    const int CB = (MP1 + 255) / 256;           // 9
    const int RB = (MP1 + 3) / 4;               // 513: 1 row per wave
    const int PB = ((MP1 + 1) / 2 + 3) / 4;     // 257: 2 rows/cols per wave

    proj_kernel<<<dim3(CB, B, 2), 256, 0, stream>>>(
        mdesc0, mdesc1, pA_w, pA_b, pB_w, pB_b, dA, dB);

    for (int it = 0; it < 3; ++it) {
        row_stream<<<dim3(RB, B), 256, 0, stream>>>(
            scores, alpha, v, rowstate, it == 0 ? 1 : 0);
        row_mlp<<<dim3(PB, B), 256, 0, stream>>>(
            rowstate, alpha, v, dA, u, it == 0 ? 1 : 0,
            rW[0], rW[1], rW[2], rW[3], rW[4], rW[5], rW[6], rW[7], rW[8], rW[9]);
        col_stream<<<dim3(4, NCHUNK, B), 256, 0, stream>>>(scores, u, partial);
        col_mlp_fused<<<dim3(PB, B), 256, 0, stream>>>(
            partial, dB, u, alpha, v,
            cW[0], cW[1], cW[2], cW[3], cW[4], cW[5], cW[6], cW[7], cW[8], cW[9]);
    }
    final_kernel<<<dim3(MP1, B), 256, 0, stream>>>(scores, alpha, u, v, out);
}

// Round 4
// 358.616 us; speedup vs baseline: 1.1245x; 1.1245x over previous
//
#include <hip/hip_runtime.h>
#include <hip/hip_fp16.h>
#include <math.h>

#define LOG2E 1.4426950408889634f
#define LN2F  0.6931471805599453f

constexpr int M   = 2048;
constexpr int N   = 2048;
constexpr int D   = 256;
constexpr int MP1 = 2049;   // M+1 == N+1
constexpr int UVS = 2052;   // padded u/v batch stride -> float4-aligned rows
constexpr int NCHUNK = 32;
constexpr int CHUNK  = 64;  // NCHUNK*CHUNK == 2048 score rows; dustbin row added in combine

struct alignas(16) half8 { __half2 h[4]; };

__device__ inline half8 pack_half8(const float4& a, const float4& b) {
    half8 r;
    r.h[0] = __floats2half2_rn(a.x, a.y);
    r.h[1] = __floats2half2_rn(a.z, a.w);
    r.h[2] = __floats2half2_rn(b.x, b.y);
    r.h[3] = __floats2half2_rn(b.z, b.w);
    return r;
}

__device__ inline float fast_exp2(float x) {
#if __has_builtin(__builtin_amdgcn_exp2f)
    return __builtin_amdgcn_exp2f(x);
#else
    return exp2f(x);
#endif
}
__device__ inline float fast_log2(float x) {
#if __has_builtin(__builtin_amdgcn_logf)
    return __builtin_amdgcn_logf(x);   // v_log_f32 is log2
#else
    return log2f(x);
#endif
}
// NaN-guarded exp2 for identity (-inf) merges
__device__ inline float exp2g(float x) { return fast_exp2(fmaxf(x, -20000.0f)); }

__device__ inline void insert5(float t[5], float y) {
    float v = y, mx;
    #pragma unroll
    for (int k = 0; k < 5; ++k) { mx = fmaxf(t[k], v); v = fminf(t[k], v); t[k] = mx; }
}

// descending compare-exchange: a <- max, b <- min
__device__ inline void ce_desc(float& a, float& b) {
    float hi = fmaxf(a, b), lo = fminf(a, b); a = hi; b = lo;
}
// 19-CE sorting network for 8 elements, descending (y[0] = max). ILP-friendly.
__device__ inline void sort8_desc(float y[8]) {
    ce_desc(y[0],y[1]); ce_desc(y[2],y[3]); ce_desc(y[4],y[5]); ce_desc(y[6],y[7]);
    ce_desc(y[0],y[2]); ce_desc(y[1],y[3]); ce_desc(y[4],y[6]); ce_desc(y[5],y[7]);
    ce_desc(y[1],y[2]); ce_desc(y[5],y[6]); ce_desc(y[0],y[4]); ce_desc(y[3],y[7]);
    ce_desc(y[1],y[5]); ce_desc(y[2],y[6]);
    ce_desc(y[1],y[4]); ce_desc(y[3],y[6]);
    ce_desc(y[2],y[4]); ce_desc(y[3],y[5]);
    ce_desc(y[3],y[4]);
}

// merge sorted-desc top5 lists + lse states
__device__ inline void merge5(float a[5], float& as, const float b[5], float bs) {
    float r0 = fmaxf(a[0], b[0]);
    float r1 = fmaxf(fmaxf(a[1], b[1]), fminf(a[0], b[0]));
    float r2 = fmaxf(fmaxf(a[2], b[2]), fmaxf(fminf(a[1], b[0]), fminf(a[0], b[1])));
    float r3 = fmaxf(fmaxf(a[3], b[3]),
               fmaxf(fmaxf(fminf(a[2], b[0]), fminf(a[1], b[1])), fminf(a[0], b[2])));
    float r4 = fmaxf(fmaxf(a[4], b[4]),
               fmaxf(fmaxf(fminf(a[3], b[0]), fminf(a[2], b[1])),
                     fmaxf(fminf(a[1], b[2]), fminf(a[0], b[3]))));
    as = as * exp2g(a[0] - r0) + bs * exp2g(b[0] - r0);
    a[0] = r0; a[1] = r1; a[2] = r2; a[3] = r3; a[4] = r4;
}

__device__ inline void merge5_shfl_xor(float t[5], float& s, int off) {
    float b[5], bs;
    #pragma unroll
    for (int k = 0; k < 5; ++k) b[k] = __shfl_xor(t[k], off, 64);
    bs = __shfl_xor(s, off, 64);
    merge5(t, s, b, bs);
}

// dual butterfly level: two independent states interleaved
__device__ inline void merge5_shfl_xor2(float tA[5], float& sA, float tB[5], float& sB, int off) {
    float bA[5], bB[5];
    #pragma unroll
    for (int k = 0; k < 5; ++k) { bA[k] = __shfl_xor(tA[k], off, 64); bB[k] = __shfl_xor(tB[k], off, 64); }
    float bsA = __shfl_xor(sA, off, 64);
    float bsB = __shfl_xor(sB, off, 64);
    merge5(tA, sA, bA, bsA);
    merge5(tB, sB, bB, bsB);
}

// online add of one element to (t,s) state
__device__ inline void online_add(float t[5], float& s, float y) {
    float m_old = t[0];
    float m_new = fmaxf(m_old, y);
    s = s * exp2g(m_old - m_new) + fast_exp2(y - m_new);
    insert5(t, y);
}

// sort a group of 8, compute group lse-state, fold into accumulator.
__device__ inline void group_accum(bool first, float t[5], float& s, float z[8]) {
    sort8_desc(z);
    float gs = 1.0f;
    #pragma unroll
    for (int k = 1; k < 8; ++k) gs += fast_exp2(z[k] - z[0]);
    if (first) { t[0]=z[0]; t[1]=z[1]; t[2]=z[2]; t[3]=z[3]; t[4]=z[4]; s = gs; }
    else merge5(t, s, z, gs);
}

__device__ inline float gelu_exact(float x) {
    return 0.5f * x * (1.0f + erff(x * 0.70710678118654752f));
}

__device__ inline float wave_sum(float x) {
    #pragma unroll
    for (int off = 32; off >= 1; off >>= 1) x += __shfl_xor(x, off, 64);
    return x;
}
__device__ inline void wave_sum2(float& x, float& y) {
    #pragma unroll
    for (int off = 32; off >= 1; off >>= 1) {
        float xs = __shfl_xor(x, off, 64);
        float ys = __shfl_xor(y, off, 64);
        x += xs; y += ys;
    }
}

// one-wave MLP: 16 -> 64 gelu LN -> 64 gelu LN -> 1. f[] lane-uniform, j = lane.
__device__ inline float mlp_wave(const float f[16], int j,
    const float* __restrict__ w1, const float* __restrict__ b1,
    const float* __restrict__ g1, const float* __restrict__ be1,
    const float* __restrict__ w2, const float* __restrict__ b2,
    const float* __restrict__ g2, const float* __restrict__ be2,
    const float* __restrict__ w3, const float* __restrict__ b3)
{
    float h = b1[j];
    #pragma unroll
    for (int k = 0; k < 16; ++k) h = fmaf(f[k], w1[j * 16 + k], h);
    h = gelu_exact(h);
    float mu  = wave_sum(h) * (1.0f / 64.0f);
    float d   = h - mu;
    float var = wave_sum(d * d) * (1.0f / 64.0f);
    float hn  = d * rsqrtf(var + 1e-5f) * g1[j] + be1[j];
    float h2 = b2[j];
    #pragma unroll
    for (int k = 0; k < 64; ++k) h2 = fmaf(__shfl(hn, k, 64), w2[j * 64 + k], h2);
    h2 = gelu_exact(h2);
    mu  = wave_sum(h2) * (1.0f / 64.0f);
    d   = h2 - mu;
    var = wave_sum(d * d) * (1.0f / 64.0f);
    float hn2 = d * rsqrtf(var + 1e-5f) * g2[j] + be2[j];
    return wave_sum(hn2 * w3[j]) + b3[0];
}

// dual MLP: two independent rows through the same weights
__device__ inline void mlp_wave2(const float fA[16], const float fB[16], int j,
    const float* __restrict__ w1, const float* __restrict__ b1,
    const float* __restrict__ g1, const float* __restrict__ be1,
    const float* __restrict__ w2, const float* __restrict__ b2,
    const float* __restrict__ g2, const float* __restrict__ be2,
    const float* __restrict__ w3, const float* __restrict__ b3,
    float& oA, float& oB)
{
    float hA = b1[j], hB = hA;
    #pragma unroll
    for (int k = 0; k < 16; ++k) {
        float w = w1[j * 16 + k];
        hA = fmaf(fA[k], w, hA);
        hB = fmaf(fB[k], w, hB);
    }
    hA = gelu_exact(hA); hB = gelu_exact(hB);
    float muA = hA, muB = hB;
    wave_sum2(muA, muB);
    muA *= (1.0f / 64.0f); muB *= (1.0f / 64.0f);
    float dA = hA - muA, dB = hB - muB;
    float vA = dA * dA, vB = dB * dB;
    wave_sum2(vA, vB);
    vA *= (1.0f / 64.0f); vB *= (1.0f / 64.0f);
    float hnA = dA * rsqrtf(vA + 1e-5f) * g1[j] + be1[j];
    float hnB = dB * rsqrtf(vB + 1e-5f) * g1[j] + be1[j];

    float a0A = b2[j], a1A = 0.0f, a0B = b2[j], a1B = 0.0f;
    #pragma unroll
    for (int k = 0; k < 64; k += 2) {
        float w0 = w2[j * 64 + k], w1v = w2[j * 64 + k + 1];
        float sA0 = __shfl(hnA, k, 64),     sB0 = __shfl(hnB, k, 64);
        float sA1 = __shfl(hnA, k + 1, 64), sB1 = __shfl(hnB, k + 1, 64);
        a0A = fmaf(sA0, w0, a0A); a0B = fmaf(sB0, w0, a0B);
        a1A = fmaf(sA1, w1v, a1A); a1B = fmaf(sB1, w1v, a1B);
    }
    float h2A = gelu_exact(a0A + a1A), h2B = gelu_exact(a0B + a1B);
    muA = h2A; muB = h2B;
    wave_sum2(muA, muB);
    muA *= (1.0f / 64.0f); muB *= (1.0f / 64.0f);
    dA = h2A - muA; dB = h2B - muB;
    vA = dA * dA; vB = dB * dB;
    wave_sum2(vA, vB);
    vA *= (1.0f / 64.0f); vB *= (1.0f / 64.0f);
    float hn2A = dA * rsqrtf(vA + 1e-5f) * g2[j] + be2[j];
    float hn2B = dB * rsqrtf(vB + 1e-5f) * g2[j] + be2[j];
    float zA = hn2A * w3[j], zB = hn2B * w3[j];
    wave_sum2(zA, zB);
    oA = zA + b3[0];
    oB = zB + b3[0];
}

__device__ inline void feats_from(const float t[5], float s, float l2w,
                                  const float* __restrict__ dd, float f[16], float& un)
{
    float lse = t[0] + fast_log2(s);
    un = l2w - lse;
    f[0] = l2w * LN2F;
    f[1] = un  * LN2F;
    f[2] = 0.0f;
    f[3] = (t[0] - t[1]) * LN2F;
    f[4] = (t[0] - t[2]) * LN2F;
    f[5] = (t[0] - t[3]) * LN2F;
    f[6] = (t[0] - t[4]) * LN2F;
    f[7] = (lse - t[0]) * LN2F;
    #pragma unroll
    for (int p = 0; p < 8; ++p) f[8 + p] = dd[p];
}

// ---------------------------------------------------------------------------
// proj, K-split: grid (9, B, 16) [z = which*8 + ks], block 256.
// Each block: partial dot over 32 d's -> ppart[(which*B+b)*MP1 + m][ks*8+p].
// 576 blocks (vs 72 fused) -> latency hidden by TLP.
// ---------------------------------------------------------------------------
__global__ __launch_bounds__(256) void proj_part(
    const float* __restrict__ mdesc0, const float* __restrict__ mdesc1,
    const float* __restrict__ pA_w, const float* __restrict__ pB_w,
    float* __restrict__ ppart, int B)
{
    const int which = blockIdx.z >> 3;
    const int ks    = blockIdx.z & 7;
    const float* mdesc = which ? mdesc1 : mdesc0;
    const float* pw    = which ? pB_w : pA_w;

    __shared__ float swT[32 * 8];   // swT[d0*8+p]
    const int tid = threadIdx.x;
    {
        int p = tid >> 5, d0 = tid & 31;
        swT[d0 * 8 + p] = pw[p * D + ks * 32 + d0];
    }
    __syncthreads();

    const int m = blockIdx.x * 256 + tid;
    const int b = blockIdx.y;
    if (m >= M) return;   // m==M (dustbin) written as zeros by combine

    float acc[8];
    #pragma unroll
    for (int p = 0; p < 8; ++p) acc[p] = 0.0f;
    const float* base = mdesc + ((size_t)b * D + ks * 32) * M + m;
    #pragma unroll 4
    for (int d0 = 0; d0 < 32; ++d0) {
        float x = base[(size_t)d0 * M];
        #pragma unroll
        for (int p = 0; p < 8; ++p) acc[p] = fmaf(x, swT[d0 * 8 + p], acc[p]);
    }
    float4* o = (float4*)(ppart + (((size_t)(which * B + b)) * MP1 + m) * 64 + ks * 8);
    o[0] = make_float4(acc[0], acc[1], acc[2], acc[3]);
    o[1] = make_float4(acc[4], acc[5], acc[6], acc[7]);
}

// grid (9, B, 2), block 256: sum 8 K-partials + bias; dustbin row m==M -> 0
__global__ __launch_bounds__(256) void proj_combine(
    const float* __restrict__ ppart,
    const float* __restrict__ pA_b, const float* __restrict__ pB_b,
    float* __restrict__ dA, float* __restrict__ dB, int B)
{
    const int which = blockIdx.z;
    const float* pb = which ? pB_b : pA_b;
    float* dOut     = which ? dB   : dA;
    const int m = blockIdx.x * 256 + threadIdx.x;
    const int b = blockIdx.y;
    if (m > M) return;
    float* out = dOut + ((size_t)b * MP1 + m) * 8;
    if (m == M) {
        #pragma unroll
        for (int p = 0; p < 8; ++p) out[p] = 0.0f;
        return;
    }
    float acc[8];
    #pragma unroll
    for (int p = 0; p < 8; ++p) acc[p] = pb[p];
    const float4* pp = (const float4*)(ppart + (((size_t)(which * B + b)) * MP1 + m) * 64);
    #pragma unroll
    for (int ks = 0; ks < 8; ++ks) {
        float4 x0 = pp[2 * ks], x1 = pp[2 * ks + 1];
        acc[0] += x0.x; acc[1] += x0.y; acc[2] += x0.z; acc[3] += x0.w;
        acc[4] += x1.x; acc[5] += x1.y; acc[6] += x1.z; acc[7] += x1.w;
    }
    #pragma unroll
    for (int p = 0; p < 8; ++p) out[p] = acc[p];
}

// ---------------------------------------------------------------------------
// Row pass + fused MLP. grid (257, B), block 256 = 4 waves, TWO rows/wave.
// iter0: reads fp32 scores, WRITES fp16 copy (sh). iters>=1: reads fp16 sh.
// Lane owns cols [512j + 8*lane .. +7] (order-agnostic reduce).
// ---------------------------------------------------------------------------
__global__ __launch_bounds__(256) void row_fused(
    const float* __restrict__ scores, __half* __restrict__ sh,
    const float* __restrict__ alpha,
    const float* __restrict__ v, const float* __restrict__ dA,
    float* __restrict__ u, int first_iter,
    const float* __restrict__ w1, const float* __restrict__ b1,
    const float* __restrict__ g1, const float* __restrict__ be1,
    const float* __restrict__ w2, const float* __restrict__ b2,
    const float* __restrict__ g2, const float* __restrict__ be2,
    const float* __restrict__ w3, const float* __restrict__ b3)
{
    const int tid  = threadIdx.x;
    const int lane = tid & 63;
    const int wv   = tid >> 6;
    const int pair = blockIdx.x * 4 + wv;
    const int r0   = pair * 2;
    if (r0 >= MP1) return;
    const int b = blockIdx.y;

    const float alpha2 = alpha[0] * LOG2E;
    const float* vb = v + (size_t)b * UVS;
    const float4* v4 = (const float4*)vb;

    if (r0 < M) {
        float tA[5], sA, tB[5], sB;
        if (first_iter) {
            const float4* sA4 = (const float4*)(scores + ((size_t)b * M + r0) * N);
            const float4* sB4 = sA4 + (N / 4);
            half8* hA8 = (half8*)(sh + ((size_t)b * M + r0) * N);
            half8* hB8 = hA8 + (N / 8);
            #pragma unroll
            for (int j = 0; j < 4; ++j) {
                float4 qa0 = sA4[2 * lane + 128 * j], qa1 = sA4[2 * lane + 128 * j + 1];
                float4 qb0 = sB4[2 * lane + 128 * j], qb1 = sB4[2 * lane + 128 * j + 1];
                hA8[64 * j + lane] = pack_half8(qa0, qa1);
                hB8[64 * j + lane] = pack_half8(qb0, qb1);
                float zA[8] = {qa0.x*LOG2E, qa0.y*LOG2E, qa0.z*LOG2E, qa0.w*LOG2E,
                               qa1.x*LOG2E, qa1.y*LOG2E, qa1.z*LOG2E, qa1.w*LOG2E};
                float zB[8] = {qb0.x*LOG2E, qb0.y*LOG2E, qb0.z*LOG2E, qb0.w*LOG2E,
                               qb1.x*LOG2E, qb1.y*LOG2E, qb1.z*LOG2E, qb1.w*LOG2E};
                group_accum(j == 0, tA, sA, zA);
                group_accum(j == 0, tB, sB, zB);
            }
        } else {
            const half8* hA8 = (const half8*)(sh + ((size_t)b * M + r0) * N);
            const half8* hB8 = hA8 + (N / 8);
            half8 ha[4], hb[4];
            float4 vv[8];
            #pragma unroll
            for (int j = 0; j < 4; ++j) { ha[j] = hA8[64 * j + lane]; hb[j] = hB8[64 * j + lane]; }
            #pragma unroll
            for (int j = 0; j < 4; ++j) {
                vv[2 * j]     = v4[2 * lane + 128 * j];
                vv[2 * j + 1] = v4[2 * lane + 128 * j + 1];
            }
            #pragma unroll
            for (int j = 0; j < 4; ++j) {
                float2 a0 = __half22float2(ha[j].h[0]), a1 = __half22float2(ha[j].h[1]);
                float2 a2 = __half22float2(ha[j].h[2]), a3 = __half22float2(ha[j].h[3]);
                float2 b0 = __half22float2(hb[j].h[0]), b1v = __half22float2(hb[j].h[1]);
                float2 b2v = __half22float2(hb[j].h[2]), b3v = __half22float2(hb[j].h[3]);
                float4 w0 = vv[2 * j], w1v = vv[2 * j + 1];
                float zA[8] = {fmaf(a0.x,LOG2E,w0.x), fmaf(a0.y,LOG2E,w0.y),
                               fmaf(a1.x,LOG2E,w0.z), fmaf(a1.y,LOG2E,w0.w),
                               fmaf(a2.x,LOG2E,w1v.x), fmaf(a2.y,LOG2E,w1v.y),
                               fmaf(a3.x,LOG2E,w1v.z), fmaf(a3.y,LOG2E,w1v.w)};
                float zB[8] = {fmaf(b0.x,LOG2E,w0.x), fmaf(b0.y,LOG2E,w0.y),
                               fmaf(b1v.x,LOG2E,w0.z), fmaf(b1v.y,LOG2E,w0.w),
                               fmaf(b2v.x,LOG2E,w1v.x), fmaf(b2v.y,LOG2E,w1v.y),
                               fmaf(b3v.x,LOG2E,w1v.z), fmaf(b3v.y,LOG2E,w1v.w)};
                group_accum(j == 0, tA, sA, zA);
                group_accum(j == 0, tB, sB, zB);
            }
        }

        #pragma unroll
        for (int off = 32; off >= 1; off >>= 1) merge5_shfl_xor2(tA, sA, tB, sB, off);

        float extra = first_iter ? alpha2 : (alpha2 + vb[N]);
        online_add(tA, sA, extra);
        online_add(tB, sB, extra);

        float fA[16], fB[16], unA, unB;
        const float* ddA = dA + (size_t)(b * MP1 + r0) * 8;
        feats_from(tA, sA, -12.0f, ddA, fA, unA);
        feats_from(tB, sB, -12.0f, ddA + 8, fB, unB);

        float oA, oB;
        mlp_wave2(fA, fB, lane, w1, b1, g1, be1, w2, b2, g2, be2, w3, b3, oA, oB);
        if (lane == 0) {
            u[(size_t)b * UVS + r0]     = unA + oA * LOG2E;
            u[(size_t)b * UVS + r0 + 1] = unB + oB * LOG2E;
        }
    } else {
        // ---- dustbin row r0 == M ----
        float t[5], s;
        #pragma unroll
        for (int g = 0; g < 4; ++g) {
            float z[8];
            if (first_iter) {
                #pragma unroll
                for (int k = 0; k < 8; ++k) z[k] = alpha2;
            } else {
                float4 wa = v4[lane + 128 * g];
                float4 wb = v4[lane + 128 * g + 64];
                z[0]=alpha2+wa.x; z[1]=alpha2+wa.y; z[2]=alpha2+wa.z; z[3]=alpha2+wa.w;
                z[4]=alpha2+wb.x; z[5]=alpha2+wb.y; z[6]=alpha2+wb.z; z[7]=alpha2+wb.w;
            }
            group_accum(g == 0, t, s, z);
        }
        #pragma unroll
        for (int off = 32; off >= 1; off >>= 1) merge5_shfl_xor(t, s, off);
        float extra = first_iter ? alpha2 : (alpha2 + vb[N]);
        online_add(t, s, extra);

        float f[16], un;
        const float* dd = dA + (size_t)(b * MP1 + M) * 8;
        feats_from(t, s, -1.0f, dd, f, un);
        float o = mlp_wave(f, lane, w1, b1, g1, be1, w2, b2, g2, be2, w3, b3);
        if (lane == 0) u[(size_t)b * UVS + M] = un + o * LOG2E;
    }
}

// ---------------------------------------------------------------------------
// Col pass (fp16): grid (4, NCHUNK=32, B), block 256. Thread owns TWO columns
// (__half2 loads), reduces CHUNK=64 rows as 8 sort8-groups per column.
// partial layout: [b][chunk][c][8]
// ---------------------------------------------------------------------------
__global__ __launch_bounds__(256) void col_stream(
    const __half* __restrict__ sh,
    const float* __restrict__ u, float* __restrict__ partial)
{
    const int tid = threadIdx.x;
    const int chunk = blockIdx.y;
    const int b = blockIdx.z;
    const int r0 = chunk * CHUNK;
    const int c0 = blockIdx.x * 512 + tid * 2;

    const float* __restrict__ ub = u + (size_t)b * UVS + r0;
    const __half2* base = (const __half2*)(sh + (size_t)b * M * N + (size_t)r0 * N + c0);

    float tA[5], sA, tB[5], sB;
    #pragma unroll
    for (int g = 0; g < 8; ++g) {
        __half2 q[8];
        #pragma unroll
        for (int k = 0; k < 8; ++k) q[k] = base[(size_t)(8 * g + k) * (N / 2)];
        float zA[8], zB[8];
        #pragma unroll
        for (int k = 0; k < 8; ++k) {
            float2 p = __half22float2(q[k]);
            float uu = ub[8 * g + k];
            zA[k] = fmaf(p.x, LOG2E, uu);
            zB[k] = fmaf(p.y, LOG2E, uu);
        }
        group_accum(g == 0, tA, sA, zA);
        group_accum(g == 0, tB, sB, zB);
    }

    float4* pq = (float4*)(partial + (((size_t)(b * NCHUNK + chunk) * MP1) + c0) * 8);
    pq[0] = make_float4(tA[0], tA[1], tA[2], tA[3]);
    pq[1] = make_float4(tA[4], sA, 0.0f, 0.0f);
    pq[2] = make_float4(tB[0], tB[1], tB[2], tB[3]);
    pq[3] = make_float4(tB[4], sB, 0.0f, 0.0f);
}

// ---------------------------------------------------------------------------
// Col combine + fused MLP: grid (257, B), block 256 = 4 waves, TWO cols per
// wave. lane<NCHUNK loads both columns' partials; dual butterfly; dustbin row
// add; dual MLP. Dustbin column (c==N) wave reduces alpha2+u[] itself.
// ---------------------------------------------------------------------------
__global__ __launch_bounds__(256) void col_mlp_fused(
    const float* __restrict__ partial, const float* __restrict__ dB,
    const float* __restrict__ u, const float* __restrict__ alpha,
    float* __restrict__ v,
    const float* __restrict__ w1, const float* __restrict__ b1,
    const float* __restrict__ g1, const float* __restrict__ be1,
    const float* __restrict__ w2, const float* __restrict__ b2,
    const float* __restrict__ g2, const float* __restrict__ be2,
    const float* __restrict__ w3, const float* __restrict__ b3)
{
    const int tid  = threadIdx.x;
    const int lane = tid & 63;
    const int wv   = tid >> 6;
    const int pair = blockIdx.x * 4 + wv;
    const int c0   = pair * 2;
    if (c0 >= MP1) return;
    const int b = blockIdx.y;
    const float alpha2 = alpha[0] * LOG2E;
    const float uM = u[(size_t)b * UVS + M];

    if (c0 < N) {
        float tA[5], sA, tB[5], sB;
        if (lane < NCHUNK) {
            const float4* pq = (const float4*)(partial + (((size_t)(b * NCHUNK + lane) * MP1) + c0) * 8);
            float4 a0 = pq[0], a1 = pq[1], b0 = pq[2], b1v = pq[3];
            tA[0]=a0.x; tA[1]=a0.y; tA[2]=a0.z; tA[3]=a0.w; tA[4]=a1.x; sA=a1.y;
            tB[0]=b0.x; tB[1]=b0.y; tB[2]=b0.z; tB[3]=b0.w; tB[4]=b1v.x; sB=b1v.y;
        } else {
            #pragma unroll
            for (int k = 0; k < 5; ++k) { tA[k] = -INFINITY; tB[k] = -INFINITY; }
            sA = 0.0f; sB = 0.0f;
        }
        #pragma unroll
        for (int off = 32; off >= 1; off >>= 1) merge5_shfl_xor2(tA, sA, tB, sB, off);

        float extra = alpha2 + uM;   // dustbin row element
        online_add(tA, sA, extra);
        online_add(tB, sB, extra);

        float fA[16], fB[16], vnA, vnB;
        const float* ddA = dB + (size_t)(b * MP1 + c0) * 8;
        feats_from(tA, sA, -12.0f, ddA, fA, vnA);
        feats_from(tB, sB, -12.0f, ddA + 8, fB, vnB);

        float oA, oB;
        mlp_wave2(fA, fB, lane, w1, b1, g1, be1, w2, b2, g2, be2, w3, b3, oA, oB);
        if (lane == 0) {
            v[(size_t)b * UVS + c0]     = vnA + oA * LOG2E;
            v[(size_t)b * UVS + c0 + 1] = vnB + oB * LOG2E;
        }
    } else {
        // ---- dustbin column c == N: reduce alpha2 + u[r] over r=0..M ----
        const float4* u4 = (const float4*)(u + (size_t)b * UVS);
        float4 qq[8];
        #pragma unroll
        for (int j = 0; j < 8; ++j) qq[j] = u4[lane + 64 * j];
        float t[5], s;
        #pragma unroll
        for (int g = 0; g < 4; ++g) {
            float4 qa = qq[2 * g], qb = qq[2 * g + 1];
            float z[8];
            z[0]=alpha2+qa.x; z[1]=alpha2+qa.y; z[2]=alpha2+qa.z; z[3]=alpha2+qa.w;
            z[4]=alpha2+qb.x; z[5]=alpha2+qb.y; z[6]=alpha2+qb.z; z[7]=alpha2+qb.w;
            group_accum(g == 0, t, s, z);
        }
        #pragma unroll
        for (int off = 32; off >= 1; off >>= 1) merge5_shfl_xor(t, s, off);
        online_add(t, s, alpha2 + uM);   // corner element S[M,N]

        float f[16], vn;
        const float* dd = dB + (size_t)(b * MP1 + N) * 8;
        feats_from(t, s, -1.0f, dd, f, vn);
        float o = mlp_wave(f, lane, w1, b1, g1, be1, w2, b2, g2, be2, w3, b3);
        if (lane == 0) v[(size_t)b * UVS + N] = vn + o * LOG2E;
    }
}

// ---------------------------------------------------------------------------
// out[b,r,c] = S*LOG2E + u[b,r] + v[b,c] + 12.  grid (2049, B), block 256.
// Reads fp16 sh (small, L3-hot); write-dominated.
// ---------------------------------------------------------------------------
__global__ __launch_bounds__(256) void final_kernel(
    const __half* __restrict__ sh, const float* __restrict__ alpha,
    const float* __restrict__ u, const float* __restrict__ v,
    float* __restrict__ out)
{
    const int r = blockIdx.x;
    const int b = blockIdx.y;
    const int tid = threadIdx.x;
    const float alpha2 = alpha[0] * LOG2E;
    const float* vb = v + (size_t)b * UVS;
    const float ur = u[(size_t)b * UVS + r] + 12.0f;
    float* orow = out + ((size_t)b * MP1 + r) * MP1;

    if (r < M) {
        const __half* shrow = sh + ((size_t)b * M + r) * N;
        #pragma unroll
        for (int k = 0; k < 8; ++k) {
            int c = tid + 256 * k;
            orow[c] = fmaf(__half2float(shrow[c]), LOG2E, ur + vb[c]);
        }
    } else {
        #pragma unroll
        for (int k = 0; k < 8; ++k) {
            int c = tid + 256 * k;
            orow[c] = alpha2 + ur + vb[c];
        }
    }
    if (tid == 0) orow[N] = alpha2 + ur + vb[N];
}

extern "C" void kernel_launch(void* const* d_in, const int* in_sizes, int n_in,
                              void* d_out, int out_size, void* d_ws, size_t ws_size,
                              hipStream_t stream) {
    const float* scores = (const float*)d_in[0];
    const float* alpha  = (const float*)d_in[1];
    const float* mdesc0 = (const float*)d_in[2];
    const float* mdesc1 = (const float*)d_in[3];
    const float* pA_w = (const float*)d_in[4];
    const float* pA_b = (const float*)d_in[5];
    const float* pB_w = (const float*)d_in[6];
    const float* pB_b = (const float*)d_in[7];
    const float* rW[10]; const float* cW[10];
    for (int k = 0; k < 10; ++k) rW[k] = (const float*)d_in[8 + k];
    for (int k = 0; k < 10; ++k) cW[k] = (const float*)d_in[18 + k];
    float* out = (float*)d_out;

    const int B = in_sizes[0] / (M * N);

    float* ws = (float*)d_ws;
    float* u       = ws;                              // B*UVS
    float* v       = u + (size_t)B * UVS;             // B*UVS
    float* dA      = v + (size_t)B * UVS;             // B*MP1*8
    float* dB      = dA + (size_t)B * MP1 * 8;        // B*MP1*8
    float* ppart   = dB + (size_t)B * MP1 * 8;        // 2*B*MP1*64
    float* partial = ppart + (size_t)2 * B * MP1 * 64;// B*NCHUNK*MP1*8
    __half* sh     = (__half*)(partial + (size_t)B * NCHUNK * MP1 * 8); // B*M*N halfs

    const int CB = (MP1 + 255) / 256;           // 9
    const int PB = ((MP1 + 1) / 2 + 3) / 4;     // 257: 2 rows/cols per wave

    proj_part<<<dim3(CB, B, 16), 256, 0, stream>>>(
        mdesc0, mdesc1, pA_w, pB_w, ppart, B);
    proj_combine<<<dim3(CB, B, 2), 256, 0, stream>>>(
        ppart, pA_b, pB_b, dA, dB, B);

    for (int it = 0; it < 3; ++it) {
        row_fused<<<dim3(PB, B), 256, 0, stream>>>(
            scores, sh, alpha, v, dA, u, it == 0 ? 1 : 0,
            rW[0], rW[1], rW[2], rW[3], rW[4], rW[5], rW[6], rW[7], rW[8], rW[9]);
        col_stream<<<dim3(4, NCHUNK, B), 256, 0, stream>>>(sh, u, partial);
        col_mlp_fused<<<dim3(PB, B), 256, 0, stream>>>(
            partial, dB, u, alpha, v,
            cW[0], cW[1], cW[2], cW[3], cW[4], cW[5], cW[6], cW[7], cW[8], cW[9]);
    }
    final_kernel<<<dim3(MP1, B), 256, 0, stream>>>(sh, alpha, u, v, out);
}

// Round 5
// 340.839 us; speedup vs baseline: 1.1831x; 1.0522x over previous
//
#include <hip/hip_runtime.h>
#include <hip/hip_fp16.h>
#include <math.h>

#define LOG2E 1.4426950408889634f
#define LN2F  0.6931471805599453f

constexpr int M   = 2048;
constexpr int N   = 2048;
constexpr int D   = 256;
constexpr int K   = 2048;   // reduce length (both directions)
constexpr int MP1 = 2049;   // M+1 == N+1
constexpr int UVS = 2052;   // padded u/v batch stride -> float4-aligned rows

struct alignas(16) half8 { __half2 h[4]; };

__device__ inline half8 pack_half8(const float4& a, const float4& b) {
    half8 r;
    r.h[0] = __floats2half2_rn(a.x, a.y);
    r.h[1] = __floats2half2_rn(a.z, a.w);
    r.h[2] = __floats2half2_rn(b.x, b.y);
    r.h[3] = __floats2half2_rn(b.z, b.w);
    return r;
}

__device__ inline float fast_exp2(float x) {
#if __has_builtin(__builtin_amdgcn_exp2f)
    return __builtin_amdgcn_exp2f(x);
#else
    return exp2f(x);
#endif
}
__device__ inline float fast_log2(float x) {
#if __has_builtin(__builtin_amdgcn_logf)
    return __builtin_amdgcn_logf(x);   // v_log_f32 is log2
#else
    return log2f(x);
#endif
}
// NaN-guarded exp2 for identity (-inf) merges
__device__ inline float exp2g(float x) { return fast_exp2(fmaxf(x, -20000.0f)); }

__device__ inline void insert5(float t[5], float y) {
    float v = y, mx;
    #pragma unroll
    for (int k = 0; k < 5; ++k) { mx = fmaxf(t[k], v); v = fminf(t[k], v); t[k] = mx; }
}

__device__ inline void ce_desc(float& a, float& b) {
    float hi = fmaxf(a, b), lo = fminf(a, b); a = hi; b = lo;
}
// 19-CE sorting network for 8 elements, descending (y[0] = max).
__device__ inline void sort8_desc(float y[8]) {
    ce_desc(y[0],y[1]); ce_desc(y[2],y[3]); ce_desc(y[4],y[5]); ce_desc(y[6],y[7]);
    ce_desc(y[0],y[2]); ce_desc(y[1],y[3]); ce_desc(y[4],y[6]); ce_desc(y[5],y[7]);
    ce_desc(y[1],y[2]); ce_desc(y[5],y[6]); ce_desc(y[0],y[4]); ce_desc(y[3],y[7]);
    ce_desc(y[1],y[5]); ce_desc(y[2],y[6]);
    ce_desc(y[1],y[4]); ce_desc(y[3],y[6]);
    ce_desc(y[2],y[4]); ce_desc(y[3],y[5]);
    ce_desc(y[3],y[4]);
}

// merge sorted-desc top5 lists + lse states
__device__ inline void merge5(float a[5], float& as, const float b[5], float bs) {
    float r0 = fmaxf(a[0], b[0]);
    float r1 = fmaxf(fmaxf(a[1], b[1]), fminf(a[0], b[0]));
    float r2 = fmaxf(fmaxf(a[2], b[2]), fmaxf(fminf(a[1], b[0]), fminf(a[0], b[1])));
    float r3 = fmaxf(fmaxf(a[3], b[3]),
               fmaxf(fmaxf(fminf(a[2], b[0]), fminf(a[1], b[1])), fminf(a[0], b[2])));
    float r4 = fmaxf(fmaxf(a[4], b[4]),
               fmaxf(fmaxf(fminf(a[3], b[0]), fminf(a[2], b[1])),
                     fmaxf(fminf(a[1], b[2]), fminf(a[0], b[3]))));
    as = as * exp2g(a[0] - r0) + bs * exp2g(b[0] - r0);
    a[0] = r0; a[1] = r1; a[2] = r2; a[3] = r3; a[4] = r4;
}

__device__ inline void merge5_shfl_xor(float t[5], float& s, int off) {
    float b[5], bs;
    #pragma unroll
    for (int k = 0; k < 5; ++k) b[k] = __shfl_xor(t[k], off, 64);
    bs = __shfl_xor(s, off, 64);
    merge5(t, s, b, bs);
}

// dual butterfly level: two independent states interleaved
__device__ inline void merge5_shfl_xor2(float tA[5], float& sA, float tB[5], float& sB, int off) {
    float bA[5], bB[5];
    #pragma unroll
    for (int k = 0; k < 5; ++k) { bA[k] = __shfl_xor(tA[k], off, 64); bB[k] = __shfl_xor(tB[k], off, 64); }
    float bsA = __shfl_xor(sA, off, 64);
    float bsB = __shfl_xor(sB, off, 64);
    merge5(tA, sA, bA, bsA);
    merge5(tB, sB, bB, bsB);
}

__device__ inline void online_add(float t[5], float& s, float y) {
    float m_old = t[0];
    float m_new = fmaxf(m_old, y);
    s = s * exp2g(m_old - m_new) + fast_exp2(y - m_new);
    insert5(t, y);
}

// sort a group of 8, compute group lse-state, fold into accumulator.
__device__ inline void group_accum(bool first, float t[5], float& s, float z[8]) {
    sort8_desc(z);
    float gs = 1.0f;
    #pragma unroll
    for (int k = 1; k < 8; ++k) gs += fast_exp2(z[k] - z[0]);
    if (first) { t[0]=z[0]; t[1]=z[1]; t[2]=z[2]; t[3]=z[3]; t[4]=z[4]; s = gs; }
    else merge5(t, s, z, gs);
}

__device__ inline float gelu_exact(float x) {
    return 0.5f * x * (1.0f + erff(x * 0.70710678118654752f));
}

__device__ inline float wave_sum(float x) {
    #pragma unroll
    for (int off = 32; off >= 1; off >>= 1) x += __shfl_xor(x, off, 64);
    return x;
}
__device__ inline void wave_sum2(float& x, float& y) {
    #pragma unroll
    for (int off = 32; off >= 1; off >>= 1) {
        float xs = __shfl_xor(x, off, 64);
        float ys = __shfl_xor(y, off, 64);
        x += xs; y += ys;
    }
}

// one-wave MLP: 16 -> 64 gelu LN -> 64 gelu LN -> 1. f[] lane-uniform, j = lane.
__device__ inline float mlp_wave(const float f[16], int j,
    const float* __restrict__ w1, const float* __restrict__ b1,
    const float* __restrict__ g1, const float* __restrict__ be1,
    const float* __restrict__ w2, const float* __restrict__ b2,
    const float* __restrict__ g2, const float* __restrict__ be2,
    const float* __restrict__ w3, const float* __restrict__ b3)
{
    float h = b1[j];
    #pragma unroll
    for (int k = 0; k < 16; ++k) h = fmaf(f[k], w1[j * 16 + k], h);
    h = gelu_exact(h);
    float mu  = wave_sum(h) * (1.0f / 64.0f);
    float d   = h - mu;
    float var = wave_sum(d * d) * (1.0f / 64.0f);
    float hn  = d * rsqrtf(var + 1e-5f) * g1[j] + be1[j];
    float h2 = b2[j];
    #pragma unroll
    for (int k = 0; k < 64; ++k) h2 = fmaf(__shfl(hn, k, 64), w2[j * 64 + k], h2);
    h2 = gelu_exact(h2);
    mu  = wave_sum(h2) * (1.0f / 64.0f);
    d   = h2 - mu;
    var = wave_sum(d * d) * (1.0f / 64.0f);
    float hn2 = d * rsqrtf(var + 1e-5f) * g2[j] + be2[j];
    return wave_sum(hn2 * w3[j]) + b3[0];
}

// dual MLP: two independent rows through the same weights
__device__ inline void mlp_wave2(const float fA[16], const float fB[16], int j,
    const float* __restrict__ w1, const float* __restrict__ b1,
    const float* __restrict__ g1, const float* __restrict__ be1,
    const float* __restrict__ w2, const float* __restrict__ b2,
    const float* __restrict__ g2, const float* __restrict__ be2,
    const float* __restrict__ w3, const float* __restrict__ b3,
    float& oA, float& oB)
{
    float hA = b1[j], hB = hA;
    #pragma unroll
    for (int k = 0; k < 16; ++k) {
        float w = w1[j * 16 + k];
        hA = fmaf(fA[k], w, hA);
        hB = fmaf(fB[k], w, hB);
    }
    hA = gelu_exact(hA); hB = gelu_exact(hB);
    float muA = hA, muB = hB;
    wave_sum2(muA, muB);
    muA *= (1.0f / 64.0f); muB *= (1.0f / 64.0f);
    float dA = hA - muA, dB = hB - muB;
    float vA = dA * dA, vB = dB * dB;
    wave_sum2(vA, vB);
    vA *= (1.0f / 64.0f); vB *= (1.0f / 64.0f);
    float hnA = dA * rsqrtf(vA + 1e-5f) * g1[j] + be1[j];
    float hnB = dB * rsqrtf(vB + 1e-5f) * g1[j] + be1[j];

    float a0A = b2[j], a1A = 0.0f, a0B = b2[j], a1B = 0.0f;
    #pragma unroll
    for (int k = 0; k < 64; k += 2) {
        float w0 = w2[j * 64 + k], w1v = w2[j * 64 + k + 1];
        float sA0 = __shfl(hnA, k, 64),     sB0 = __shfl(hnB, k, 64);
        float sA1 = __shfl(hnA, k + 1, 64), sB1 = __shfl(hnB, k + 1, 64);
        a0A = fmaf(sA0, w0, a0A); a0B = fmaf(sB0, w0, a0B);
        a1A = fmaf(sA1, w1v, a1A); a1B = fmaf(sB1, w1v, a1B);
    }
    float h2A = gelu_exact(a0A + a1A), h2B = gelu_exact(a0B + a1B);
    muA = h2A; muB = h2B;
    wave_sum2(muA, muB);
    muA *= (1.0f / 64.0f); muB *= (1.0f / 64.0f);
    dA = h2A - muA; dB = h2B - muB;
    vA = dA * dA; vB = dB * dB;
    wave_sum2(vA, vB);
    vA *= (1.0f / 64.0f); vB *= (1.0f / 64.0f);
    float hn2A = dA * rsqrtf(vA + 1e-5f) * g2[j] + be2[j];
    float hn2B = dB * rsqrtf(vB + 1e-5f) * g2[j] + be2[j];
    float zA = hn2A * w3[j], zB = hn2B * w3[j];
    wave_sum2(zA, zB);
    oA = zA + b3[0];
    oB = zB + b3[0];
}

__device__ inline void feats_from(const float t[5], float s, float l2w,
                                  const float* __restrict__ dd, float f[16], float& un)
{
    float lse = t[0] + fast_log2(s);
    un = l2w - lse;
    f[0] = l2w * LN2F;
    f[1] = un  * LN2F;
    f[2] = 0.0f;
    f[3] = (t[0] - t[1]) * LN2F;
    f[4] = (t[0] - t[2]) * LN2F;
    f[5] = (t[0] - t[3]) * LN2F;
    f[6] = (t[0] - t[4]) * LN2F;
    f[7] = (lse - t[0]) * LN2F;
    #pragma unroll
    for (int p = 0; p < 8; ++p) f[8 + p] = dd[p];
}

// ---------------------------------------------------------------------------
// proj, K-split: grid (9, B, 16) [z = which*8 + ks], block 256.
// ---------------------------------------------------------------------------
__global__ __launch_bounds__(256) void proj_part(
    const float* __restrict__ mdesc0, const float* __restrict__ mdesc1,
    const float* __restrict__ pA_w, const float* __restrict__ pB_w,
    float* __restrict__ ppart, int B)
{
    const int which = blockIdx.z >> 3;
    const int ks    = blockIdx.z & 7;
    const float* mdesc = which ? mdesc1 : mdesc0;
    const float* pw    = which ? pB_w : pA_w;

    __shared__ float swT[32 * 8];   // swT[d0*8+p]
    const int tid = threadIdx.x;
    {
        int p = tid >> 5, d0 = tid & 31;
        swT[d0 * 8 + p] = pw[p * D + ks * 32 + d0];
    }
    __syncthreads();

    const int m = blockIdx.x * 256 + tid;
    const int b = blockIdx.y;
    if (m >= M) return;

    float acc[8];
    #pragma unroll
    for (int p = 0; p < 8; ++p) acc[p] = 0.0f;
    const float* base = mdesc + ((size_t)b * D + ks * 32) * M + m;
    #pragma unroll 4
    for (int d0 = 0; d0 < 32; ++d0) {
        float x = base[(size_t)d0 * M];
        #pragma unroll
        for (int p = 0; p < 8; ++p) acc[p] = fmaf(x, swT[d0 * 8 + p], acc[p]);
    }
    float4* o = (float4*)(ppart + (((size_t)(which * B + b)) * MP1 + m) * 64 + ks * 8);
    o[0] = make_float4(acc[0], acc[1], acc[2], acc[3]);
    o[1] = make_float4(acc[4], acc[5], acc[6], acc[7]);
}

// grid (9, B, 2), block 256: sum 8 K-partials + bias; dustbin row m==M -> 0
__global__ __launch_bounds__(256) void proj_combine(
    const float* __restrict__ ppart,
    const float* __restrict__ pA_b, const float* __restrict__ pB_b,
    float* __restrict__ dA, float* __restrict__ dB, int B)
{
    const int which = blockIdx.z;
    const float* pb = which ? pB_b : pA_b;
    float* dOut     = which ? dB   : dA;
    const int m = blockIdx.x * 256 + threadIdx.x;
    const int b = blockIdx.y;
    if (m > M) return;
    float* out = dOut + ((size_t)b * MP1 + m) * 8;
    if (m == M) {
        #pragma unroll
        for (int p = 0; p < 8; ++p) out[p] = 0.0f;
        return;
    }
    float acc[8];
    #pragma unroll
    for (int p = 0; p < 8; ++p) acc[p] = pb[p];
    const float4* pp = (const float4*)(ppart + (((size_t)(which * B + b)) * MP1 + m) * 64);
    #pragma unroll
    for (int ks = 0; ks < 8; ++ks) {
        float4 x0 = pp[2 * ks], x1 = pp[2 * ks + 1];
        acc[0] += x0.x; acc[1] += x0.y; acc[2] += x0.z; acc[3] += x0.w;
        acc[4] += x1.x; acc[5] += x1.y; acc[6] += x1.z; acc[7] += x1.w;
    }
    #pragma unroll
    for (int p = 0; p < 8; ++p) out[p] = acc[p];
}

// ---------------------------------------------------------------------------
// Iter-0 row pass: reads fp32 scores (v==0), writes fp16 copy sh, fused MLP.
// grid (257, B), block 256 = 4 waves, TWO rows per wave.
// ---------------------------------------------------------------------------
__global__ __launch_bounds__(256) void row0_fused(
    const float* __restrict__ scores, __half* __restrict__ sh,
    const float* __restrict__ alpha, const float* __restrict__ dA,
    float* __restrict__ u,
    const float* __restrict__ w1, const float* __restrict__ b1,
    const float* __restrict__ g1, const float* __restrict__ be1,
    const float* __restrict__ w2, const float* __restrict__ b2,
    const float* __restrict__ g2, const float* __restrict__ be2,
    const float* __restrict__ w3, const float* __restrict__ b3)
{
    const int tid  = threadIdx.x;
    const int lane = tid & 63;
    const int wv   = tid >> 6;
    const int pair = blockIdx.x * 4 + wv;
    const int r0   = pair * 2;
    if (r0 >= MP1) return;
    const int b = blockIdx.y;
    const float alpha2 = alpha[0] * LOG2E;

    if (r0 < M) {
        const float4* sA4 = (const float4*)(scores + ((size_t)b * M + r0) * N);
        const float4* sB4 = sA4 + (N / 4);
        half8* hA8 = (half8*)(sh + ((size_t)b * M + r0) * N);
        half8* hB8 = hA8 + (N / 8);
        float tA[5], sA, tB[5], sB;
        #pragma unroll
        for (int j = 0; j < 4; ++j) {
            float4 qa0 = sA4[2 * lane + 128 * j], qa1 = sA4[2 * lane + 128 * j + 1];
            float4 qb0 = sB4[2 * lane + 128 * j], qb1 = sB4[2 * lane + 128 * j + 1];
            hA8[64 * j + lane] = pack_half8(qa0, qa1);
            hB8[64 * j + lane] = pack_half8(qb0, qb1);
            float zA[8] = {qa0.x*LOG2E, qa0.y*LOG2E, qa0.z*LOG2E, qa0.w*LOG2E,
                           qa1.x*LOG2E, qa1.y*LOG2E, qa1.z*LOG2E, qa1.w*LOG2E};
            float zB[8] = {qb0.x*LOG2E, qb0.y*LOG2E, qb0.z*LOG2E, qb0.w*LOG2E,
                           qb1.x*LOG2E, qb1.y*LOG2E, qb1.z*LOG2E, qb1.w*LOG2E};
            group_accum(j == 0, tA, sA, zA);
            group_accum(j == 0, tB, sB, zB);
        }

        #pragma unroll
        for (int off = 32; off >= 1; off >>= 1) merge5_shfl_xor2(tA, sA, tB, sB, off);

        online_add(tA, sA, alpha2);
        online_add(tB, sB, alpha2);

        float fA[16], fB[16], unA, unB;
        const float* ddA = dA + (size_t)(b * MP1 + r0) * 8;
        feats_from(tA, sA, -12.0f, ddA, fA, unA);
        feats_from(tB, sB, -12.0f, ddA + 8, fB, unB);

        float oA, oB;
        mlp_wave2(fA, fB, lane, w1, b1, g1, be1, w2, b2, g2, be2, w3, b3, oA, oB);
        if (lane == 0) {
            u[(size_t)b * UVS + r0]     = unA + oA * LOG2E;
            u[(size_t)b * UVS + r0 + 1] = unB + oB * LOG2E;
        }
    } else {
        // dustbin row r0 == M: all elements alpha2
        float t[5] = {alpha2, alpha2, alpha2, alpha2, alpha2};
        float s = 2049.0f;   // 2^0 summed 2049 times (2048 cols + dustbin col), max=alpha2
        float f[16], un;
        const float* dd = dA + (size_t)(b * MP1 + M) * 8;
        feats_from(t, s, -1.0f, dd, f, un);
        float o = mlp_wave(f, lane, w1, b1, g1, be1, w2, b2, g2, be2, w3, b3);
        if (lane == 0) u[(size_t)b * UVS + M] = un + o * LOG2E;
    }
}

// ---------------------------------------------------------------------------
// fp16 transpose: sh[b][r][c] -> shT[b][c][r]. 64x64 LDS tiles.
// grid (32, 32, B), block 256.
// ---------------------------------------------------------------------------
__global__ __launch_bounds__(256) void transpose_half(
    const __half* __restrict__ sh, __half* __restrict__ shT)
{
    __shared__ unsigned short a[64][65];
    const int b  = blockIdx.z;
    const int r0 = blockIdx.x * 64;
    const int c0 = blockIdx.y * 64;
    const int t  = threadIdx.x;

    const __half* src = sh + ((size_t)b * M + r0) * N + c0;
    #pragma unroll
    for (int i = 0; i < 2; ++i) {
        int s = t + 256 * i;            // 512 half8 slots
        int r = s >> 3, c8 = (s & 7) * 8;
        half8 hv = *(const half8*)(src + (size_t)r * N + c8);
        const unsigned short* pv = (const unsigned short*)&hv;
        #pragma unroll
        for (int k = 0; k < 8; ++k) a[r][c8 + k] = pv[k];
    }
    __syncthreads();
    __half* dst = shT + ((size_t)b * N + c0) * M + r0;
    #pragma unroll
    for (int i = 0; i < 2; ++i) {
        int s = t + 256 * i;
        int c = s >> 3, r8 = (s & 7) * 8;
        half8 ov;
        unsigned short* po = (unsigned short*)&ov;
        #pragma unroll
        for (int k = 0; k < 8; ++k) po[k] = a[r8 + k][c];
        *(half8*)(dst + (size_t)c * M + r8) = ov;
    }
}

// ---------------------------------------------------------------------------
// Generic fp16 reduce + fused MLP pass (rows or cols).
//   out[i] from reduce over k of mat[b][i][k]*LOG2E + vk[k]; extra element
//   (k==K) = alpha2 + vk[K]. Dustbin i==M: z[k] = alpha2 + vk[k].
// rows: mat=sh,  vk=v, desc=dA, out=u.  cols: mat=shT, vk=u, desc=dB, out=v.
// grid (257, B), block 256 = 4 waves, TWO outputs per wave.
// ---------------------------------------------------------------------------
__global__ __launch_bounds__(256) void rc_fused(
    const __half* __restrict__ mat, const float* __restrict__ vk_base,
    const float* __restrict__ desc, const float* __restrict__ alpha,
    float* __restrict__ out,
    const float* __restrict__ w1, const float* __restrict__ b1,
    const float* __restrict__ g1, const float* __restrict__ be1,
    const float* __restrict__ w2, const float* __restrict__ b2,
    const float* __restrict__ g2, const float* __restrict__ be2,
    const float* __restrict__ w3, const float* __restrict__ b3)
{
    const int tid  = threadIdx.x;
    const int lane = tid & 63;
    const int wv   = tid >> 6;
    const int pair = blockIdx.x * 4 + wv;
    const int i0   = pair * 2;
    if (i0 >= MP1) return;
    const int b = blockIdx.y;
    const float alpha2 = alpha[0] * LOG2E;
    const float* vk = vk_base + (size_t)b * UVS;
    const float4* vk4 = (const float4*)vk;

    if (i0 < M) {
        const half8* hA8 = (const half8*)(mat + ((size_t)b * M + i0) * K);
        const half8* hB8 = hA8 + (K / 8);
        half8 ha[4], hb[4];
        float4 vv[8];
        #pragma unroll
        for (int j = 0; j < 4; ++j) { ha[j] = hA8[64 * j + lane]; hb[j] = hB8[64 * j + lane]; }
        #pragma unroll
        for (int j = 0; j < 4; ++j) {
            vv[2 * j]     = vk4[2 * lane + 128 * j];
            vv[2 * j + 1] = vk4[2 * lane + 128 * j + 1];
        }
        float tA[5], sA, tB[5], sB;
        #pragma unroll
        for (int j = 0; j < 4; ++j) {
            float2 a0 = __half22float2(ha[j].h[0]), a1 = __half22float2(ha[j].h[1]);
            float2 a2 = __half22float2(ha[j].h[2]), a3 = __half22float2(ha[j].h[3]);
            float2 b0 = __half22float2(hb[j].h[0]), b1v = __half22float2(hb[j].h[1]);
            float2 b2v = __half22float2(hb[j].h[2]), b3v = __half22float2(hb[j].h[3]);
            float4 w0 = vv[2 * j], w1v = vv[2 * j + 1];
            float zA[8] = {fmaf(a0.x,LOG2E,w0.x), fmaf(a0.y,LOG2E,w0.y),
                           fmaf(a1.x,LOG2E,w0.z), fmaf(a1.y,LOG2E,w0.w),
                           fmaf(a2.x,LOG2E,w1v.x), fmaf(a2.y,LOG2E,w1v.y),
                           fmaf(a3.x,LOG2E,w1v.z), fmaf(a3.y,LOG2E,w1v.w)};
            float zB[8] = {fmaf(b0.x,LOG2E,w0.x), fmaf(b0.y,LOG2E,w0.y),
                           fmaf(b1v.x,LOG2E,w0.z), fmaf(b1v.y,LOG2E,w0.w),
                           fmaf(b2v.x,LOG2E,w1v.x), fmaf(b2v.y,LOG2E,w1v.y),
                           fmaf(b3v.x,LOG2E,w1v.z), fmaf(b3v.y,LOG2E,w1v.w)};
            group_accum(j == 0, tA, sA, zA);
            group_accum(j == 0, tB, sB, zB);
        }

        #pragma unroll
        for (int off = 32; off >= 1; off >>= 1) merge5_shfl_xor2(tA, sA, tB, sB, off);

        float extra = alpha2 + vk[K];
        online_add(tA, sA, extra);
        online_add(tB, sB, extra);

        float fA[16], fB[16], unA, unB;
        const float* ddA = desc + (size_t)(b * MP1 + i0) * 8;
        feats_from(tA, sA, -12.0f, ddA, fA, unA);
        feats_from(tB, sB, -12.0f, ddA + 8, fB, unB);

        float oA, oB;
        mlp_wave2(fA, fB, lane, w1, b1, g1, be1, w2, b2, g2, be2, w3, b3, oA, oB);
        if (lane == 0) {
            out[(size_t)b * UVS + i0]     = unA + oA * LOG2E;
            out[(size_t)b * UVS + i0 + 1] = unB + oB * LOG2E;
        }
    } else {
        // dustbin output i0 == M: z[k] = alpha2 + vk[k]
        float t[5], s;
        #pragma unroll
        for (int g = 0; g < 4; ++g) {
            float4 wa = vk4[lane + 128 * g];
            float4 wb = vk4[lane + 128 * g + 64];
            float z[8] = {alpha2+wa.x, alpha2+wa.y, alpha2+wa.z, alpha2+wa.w,
                          alpha2+wb.x, alpha2+wb.y, alpha2+wb.z, alpha2+wb.w};
            group_accum(g == 0, t, s, z);
        }
        #pragma unroll
        for (int off = 32; off >= 1; off >>= 1) merge5_shfl_xor(t, s, off);
        online_add(t, s, alpha2 + vk[K]);

        float f[16], un;
        const float* dd = desc + (size_t)(b * MP1 + M) * 8;
        feats_from(t, s, -1.0f, dd, f, un);
        float o = mlp_wave(f, lane, w1, b1, g1, be1, w2, b2, g2, be2, w3, b3);
        if (lane == 0) out[(size_t)b * UVS + M] = un + o * LOG2E;
    }
}

// ---------------------------------------------------------------------------
// out[b,r,c] = S*LOG2E + u[b,r] + v[b,c] + 12.  grid (2049, B), block 256.
// half8 loads (1 per thread), scalar coalesced stores.
// ---------------------------------------------------------------------------
__global__ __launch_bounds__(256) void final_kernel(
    const __half* __restrict__ sh, const float* __restrict__ alpha,
    const float* __restrict__ u, const float* __restrict__ v,
    float* __restrict__ out)
{
    const int r = blockIdx.x;
    const int b = blockIdx.y;
    const int tid = threadIdx.x;
    const float alpha2 = alpha[0] * LOG2E;
    const float* vb = v + (size_t)b * UVS;
    const float4* v4 = (const float4*)vb;
    const float ur = u[(size_t)b * UVS + r] + 12.0f;
    float* orow = out + ((size_t)b * MP1 + r) * MP1;

    float4 w0 = v4[2 * tid], w1v = v4[2 * tid + 1];
    const int c = tid * 8;
    if (r < M) {
        half8 hv = *(const half8*)(sh + ((size_t)b * M + r) * N + c);
        float2 a0 = __half22float2(hv.h[0]), a1 = __half22float2(hv.h[1]);
        float2 a2 = __half22float2(hv.h[2]), a3 = __half22float2(hv.h[3]);
        orow[c]     = fmaf(a0.x, LOG2E, ur + w0.x);
        orow[c + 1] = fmaf(a0.y, LOG2E, ur + w0.y);
        orow[c + 2] = fmaf(a1.x, LOG2E, ur + w0.z);
        orow[c + 3] = fmaf(a1.y, LOG2E, ur + w0.w);
        orow[c + 4] = fmaf(a2.x, LOG2E, ur + w1v.x);
        orow[c + 5] = fmaf(a2.y, LOG2E, ur + w1v.y);
        orow[c + 6] = fmaf(a3.x, LOG2E, ur + w1v.z);
        orow[c + 7] = fmaf(a3.y, LOG2E, ur + w1v.w);
    } else {
        orow[c]     = alpha2 + ur + w0.x;
        orow[c + 1] = alpha2 + ur + w0.y;
        orow[c + 2] = alpha2 + ur + w0.z;
        orow[c + 3] = alpha2 + ur + w0.w;
        orow[c + 4] = alpha2 + ur + w1v.x;
        orow[c + 5] = alpha2 + ur + w1v.y;
        orow[c + 6] = alpha2 + ur + w1v.z;
        orow[c + 7] = alpha2 + ur + w1v.w;
    }
    if (tid == 0) orow[N] = alpha2 + ur + vb[N];
}

extern "C" void kernel_launch(void* const* d_in, const int* in_sizes, int n_in,
                              void* d_out, int out_size, void* d_ws, size_t ws_size,
                              hipStream_t stream) {
    const float* scores = (const float*)d_in[0];
    const float* alpha  = (const float*)d_in[1];
    const float* mdesc0 = (const float*)d_in[2];
    const float* mdesc1 = (const float*)d_in[3];
    const float* pA_w = (const float*)d_in[4];
    const float* pA_b = (const float*)d_in[5];
    const float* pB_w = (const float*)d_in[6];
    const float* pB_b = (const float*)d_in[7];
    const float* rW[10]; const float* cW[10];
    for (int k = 0; k < 10; ++k) rW[k] = (const float*)d_in[8 + k];
    for (int k = 0; k < 10; ++k) cW[k] = (const float*)d_in[18 + k];
    float* out = (float*)d_out;

    const int B = in_sizes[0] / (M * N);

    float* ws = (float*)d_ws;
    float* u     = ws;                              // B*UVS
    float* v     = u + (size_t)B * UVS;             // B*UVS
    float* dA    = v + (size_t)B * UVS;             // B*MP1*8
    float* dB    = dA + (size_t)B * MP1 * 8;        // B*MP1*8
    float* ppart = dB + (size_t)B * MP1 * 8;        // 2*B*MP1*64
    __half* sh   = (__half*)(ppart + (size_t)2 * B * MP1 * 64); // B*M*N halfs
    __half* shT  = sh + (size_t)B * M * N;                      // B*N*M halfs

    const int CB = (MP1 + 255) / 256;           // 9
    const int PB = ((MP1 + 1) / 2 + 3) / 4;     // 257: 2 outputs per wave

    proj_part<<<dim3(CB, B, 16), 256, 0, stream>>>(
        mdesc0, mdesc1, pA_w, pB_w, ppart, B);
    proj_combine<<<dim3(CB, B, 2), 256, 0, stream>>>(
        ppart, pA_b, pB_b, dA, dB, B);

    // iter 0: row pass on fp32 (v == 0), produce sh; transpose; col pass
    row0_fused<<<dim3(PB, B), 256, 0, stream>>>(
        scores, sh, alpha, dA, u,
        rW[0], rW[1], rW[2], rW[3], rW[4], rW[5], rW[6], rW[7], rW[8], rW[9]);
    transpose_half<<<dim3(32, 32, B), 256, 0, stream>>>(sh, shT);
    rc_fused<<<dim3(PB, B), 256, 0, stream>>>(
        shT, u, dB, alpha, v,
        cW[0], cW[1], cW[2], cW[3], cW[4], cW[5], cW[6], cW[7], cW[8], cW[9]);

    for (int it = 1; it < 3; ++it) {
        rc_fused<<<dim3(PB, B), 256, 0, stream>>>(
            sh, v, dA, alpha, u,
            rW[0], rW[1], rW[2], rW[3], rW[4], rW[5], rW[6], rW[7], rW[8], rW[9]);
        rc_fused<<<dim3(PB, B), 256, 0, stream>>>(
            shT, u, dB, alpha, v,
            cW[0], cW[1], cW[2], cW[3], cW[4], cW[5], cW[6], cW[7], cW[8], cW[9]);
    }
    final_kernel<<<dim3(MP1, B), 256, 0, stream>>>(sh, alpha, u, v, out);
}